// Round 3
// baseline (552.095 us; speedup 1.0000x reference)
//
#include <hip/hip_runtime.h>
#include <hip/hip_bf16.h>

// GAT layer, N=8192, F_in=512, F_out=128.
// exp(leaky_relu(s1+s2)) = pos ? exp(s1)exp(s2) : exp(.2 s1)exp(.2 s2)
// r3: adj -> 8MB bitmask in a streaming ballot pre-pass (BW-bound, latency-
// tolerant); k2's inner loop has NO HBM loads (mask in regs, pE L1, hT L2).
// k2 fully unrolled (static mask indexing), launch_bounds(256,4).
// JS=8 col-split (1024 blocks = 4/CU); k1 re-tiled to 1024 blocks.

typedef __attribute__((ext_vector_type(4))) float f32x4;
typedef __attribute__((ext_vector_type(8))) short s16x8;

#define N_NODES 8192
#define F_IN 512
#define F_OUT 128
#define JS 8
#define JCHUNK (N_NODES / JS)   // 1024

static __device__ __forceinline__ short f2bf(float f) {
  __hip_bfloat16 h = __float2bfloat16(f);
  return __builtin_bit_cast(short, h);
}

// ------- k_mask: adj(int32 NxN) -> bitmask, bit(col&63) of word col/64 ------
__global__ __launch_bounds__(256) void k_mask(const int* __restrict__ adj,
    unsigned long long* __restrict__ mask) {
  const int nwaves = gridDim.x * 4;
  int wid = blockIdx.x * 4 + (threadIdx.x >> 6);
  int lane = threadIdx.x & 63;
  const int ntasks = N_NODES * (N_NODES / 64);   // 1,048,576 wave-tasks
  for (int task = wid; task < ntasks; task += nwaves) {
    int row = task >> 7;
    int cg = task & 127;
    int v = adj[(size_t)row * N_NODES + cg * 64 + lane];
    unsigned long long b = __ballot(v != 0);
    if (lane == 0) mask[(size_t)row * (N_NODES / 64) + cg] = b;
  }
}

// ---------------- k0a: W (512x128 f32) -> WT (128x512 bf16) ----------------
__global__ void k0a_wt(const float* __restrict__ W, unsigned short* __restrict__ WT) {
  int idx = blockIdx.x * 256 + threadIdx.x;
  int k = idx >> 7, f = idx & 127;
  WT[(size_t)f * F_IN + k] = (unsigned short)f2bf(W[idx]);
}

// ---------------- k0c: wa1[k] = sum_f W[k][f] a1[f]; wa2 likewise ----------
__global__ void k0c_wa(const float* __restrict__ W, const float* __restrict__ a,
                       float* __restrict__ wa) {
  int k = blockIdx.x * 256 + threadIdx.x;
  if (k >= F_IN) return;
  const float* Wr = W + (size_t)k * F_OUT;
  float d1 = 0.f, d2 = 0.f;
#pragma unroll 8
  for (int f = 0; f < F_OUT; f += 4) {
    f32x4 w  = *(const f32x4*)(Wr + f);
    f32x4 a1 = *(const f32x4*)(a + f);
    f32x4 a2 = *(const f32x4*)(a + F_OUT + f);
    d1 += w[0] * a1[0] + w[1] * a1[1] + w[2] * a1[2] + w[3] * a1[3];
    d2 += w[0] * a2[0] + w[1] * a2[1] + w[2] * a2[2] + w[3] * a2[3];
  }
  wa[k] = d1;
  wa[F_IN + k] = d2;
}

// ------- k0b: Xb = bf16(X); s1,s2 = X@wa per row; rowdat + pE tables -------
__global__ __launch_bounds__(256) void k0b_x(const float* __restrict__ X,
    const float* __restrict__ wa, unsigned short* __restrict__ Xb,
    f32x4* __restrict__ rowdat, unsigned* __restrict__ pE) {
  int wave = threadIdx.x >> 6, lane = threadIdx.x & 63;
  int i = blockIdx.x * 4 + wave;            // one wave per row
  const float* Xr = X + (size_t)i * F_IN + lane * 8;
  f32x4 x0 = ((const f32x4*)Xr)[0];
  f32x4 x1 = ((const f32x4*)Xr)[1];
  f32x4 w10 = ((const f32x4*)(wa + lane * 8))[0];
  f32x4 w11 = ((const f32x4*)(wa + lane * 8))[1];
  f32x4 w20 = ((const f32x4*)(wa + F_IN + lane * 8))[0];
  f32x4 w21 = ((const f32x4*)(wa + F_IN + lane * 8))[1];

  s16x8 xb;
#pragma unroll
  for (int e = 0; e < 4; e++) { xb[e] = f2bf(x0[e]); xb[e + 4] = f2bf(x1[e]); }
  *(s16x8*)(Xb + (size_t)i * F_IN + lane * 8) = xb;

  float d1 = 0.f, d2 = 0.f;
#pragma unroll
  for (int e = 0; e < 4; e++) {
    d1 += x0[e] * w10[e] + x1[e] * w11[e];
    d2 += x0[e] * w20[e] + x1[e] * w21[e];
  }
#pragma unroll
  for (int m = 1; m < 64; m <<= 1) {
    d1 += __shfl_xor(d1, m, 64);
    d2 += __shfl_xor(d2, m, 64);
  }
  if (lane == 0) {
    float s1 = d1, s2 = d2;
    f32x4 rd;
    rd[0] = expf(s1);          // E1
    rd[1] = expf(0.2f * s1);   // E1s
    rd[2] = expf(-s1);         // T1: pos <=> E2 > T1
    rd[3] = 0.f;
    rowdat[i] = rd;
    unsigned e2  = (unsigned)(unsigned short)f2bf(expf(s2));
    unsigned e2s = (unsigned)(unsigned short)f2bf(expf(0.2f * s2));
    pE[i] = (e2s << 16) | e2;
  }
}

// ------- k1: hT[f][node] = sum_k WT[f][k] Xb[node][k]; 1 tile per wave -----
__global__ __launch_bounds__(256) void k1_gemm(const unsigned short* __restrict__ WT,
    const unsigned short* __restrict__ Xb, unsigned short* __restrict__ hT) {
  int wave = threadIdx.x >> 6, lane = threadIdx.x & 63;
  int lrow = lane & 15, grp = lane >> 4;
  int tile = blockIdx.x * 4 + wave;              // 4096 tiles
  int fb = tile & 7;                             // 8 f-tiles of 16
  int nb = tile >> 3;                            // 512 node-tiles of 16

  const unsigned short* Ar = WT + (size_t)(fb * 16 + lrow) * F_IN + grp * 8;
  const unsigned short* Br = Xb + (size_t)(nb * 16 + lrow) * F_IN + grp * 8;

  f32x4 acc = (f32x4)(0.0f);
#pragma unroll
  for (int k0 = 0; k0 < F_IN; k0 += 32) {
    s16x8 af = *(const s16x8*)(Ar + k0);
    s16x8 bf = *(const s16x8*)(Br + k0);
    acc = __builtin_amdgcn_mfma_f32_16x16x32_bf16(af, bf, acc, 0, 0, 0);
  }
#pragma unroll
  for (int r = 0; r < 4; r++)
    hT[(size_t)(fb * 16 + grp * 4 + r) * N_NODES + nb * 16 + lrow] =
        (unsigned short)f2bf(acc[r]);
}

// ------- k2: one-pass masked P@h + row sums; mask in regs, no HBM loads ----
__global__ __launch_bounds__(256, 4) void k2_main(const unsigned* __restrict__ mask32,
    const unsigned short* __restrict__ hT, const f32x4* __restrict__ rowdat,
    const unsigned* __restrict__ pE, float* __restrict__ accws,
    float* __restrict__ denws) {
  int js = blockIdx.x & (JS - 1);
  int rb = blockIdx.x / JS;
  int wave = threadIdx.x >> 6, lane = threadIdx.x & 63;
  int lrow = lane & 15, grp = lane >> 4;
  int waveRow = rb * 64 + wave * 16;
  int i0 = waveRow + lrow;
  int jlo = js * JCHUNK;

  f32x4 rd = rowdat[i0];
  float E1 = rd[0], E1s = rd[1], T1 = rd[2];

  f32x4 acc[8];
#pragma unroll
  for (int n = 0; n < 8; n++) acc[n] = (f32x4)(0.0f);
  float dsum = 0.f;

#define PROC(pe, e)                                                  \
  {                                                                  \
    unsigned pu = (pe);                                              \
    float E2  = __builtin_bit_cast(float, pu << 16);                 \
    float E2s = __builtin_bit_cast(float, pu & 0xffff0000u);         \
    float sel = (E2 > T1) ? E1 * E2 : E1s * E2s;                     \
    float p = ((b >> e) & 1u) ? sel : 0.f;                           \
    dsum += p;                                                       \
    af[e] = f2bf(p);                                                 \
  }

  for (int sc = 0; sc < JCHUNK / 512; sc++) {
    int jbase = jlo + sc * 512;
    const uint4* mrow =
        (const uint4*)(mask32 + (size_t)i0 * (N_NODES / 32) + jbase / 32);
    uint4 mm[4];
#pragma unroll
    for (int c = 0; c < 4; c++) mm[c] = mrow[c];

#pragma unroll
    for (int t = 0; t < 16; t++) {
      int jj = jbase + t * 32 + grp * 8;
      unsigned b = (mm[t >> 2][t & 3] >> (grp * 8)) & 0xffu;
      const uint4* pp = (const uint4*)(pE + jj);
      uint4 P0 = pp[0], P1 = pp[1];
      s16x8 af;
      PROC(P0.x, 0); PROC(P0.y, 1); PROC(P0.z, 2); PROC(P0.w, 3);
      PROC(P1.x, 4); PROC(P1.y, 5); PROC(P1.z, 6); PROC(P1.w, 7);
      const unsigned short* hTj = hT + jj;
#pragma unroll
      for (int n = 0; n < 8; n++) {
        s16x8 bf = *(const s16x8*)(hTj + (size_t)(n * 16 + lrow) * N_NODES);
        acc[n] = __builtin_amdgcn_mfma_f32_16x16x32_bf16(af, bf, acc[n], 0, 0, 0);
      }
    }
  }
#undef PROC

  // row denominator: lanes l, l^16, l^32, l^48 share lrow (same row i)
  dsum += __shfl_xor(dsum, 16, 64);
  dsum += __shfl_xor(dsum, 32, 64);
  if (lane < 16) denws[js * N_NODES + waveRow + lane] = dsum;

#pragma unroll
  for (int n = 0; n < 8; n++)
#pragma unroll
    for (int r = 0; r < 4; r++)
      accws[((size_t)js * N_NODES + waveRow + grp * 4 + r) * F_OUT + n * 16 + lrow] =
          acc[n][r];
}

// ---------------- k3: combine partials, normalize, elu (float4) -----------
__global__ void k3_fin(const float* __restrict__ accws,
                       const float* __restrict__ denws, float* __restrict__ out) {
  int idx4 = blockIdx.x * 256 + threadIdx.x;    // 262144 float4s
  int i = idx4 >> 5;                            // row = idx4*4 / 128
  const int S4 = N_NODES * F_OUT / 4;
  f32x4 s = (f32x4)(0.0f);
  float d = 0.f;
#pragma unroll
  for (int js = 0; js < JS; js++) {
    s += ((const f32x4*)accws)[idx4 + js * S4];
    d += denws[i + js * N_NODES];
  }
  f32x4 v = s / d;
#pragma unroll
  for (int e = 0; e < 4; e++) v[e] = v[e] > 0.f ? v[e] : expm1f(v[e]);
  ((f32x4*)out)[idx4] = v;
}

extern "C" void kernel_launch(void* const* d_in, const int* in_sizes, int n_in,
                              void* d_out, int out_size, void* d_ws, size_t ws_size,
                              hipStream_t stream) {
  const float* X   = (const float*)d_in[0];
  const int*   adj = (const int*)d_in[1];
  const float* W   = (const float*)d_in[2];
  const float* a   = (const float*)d_in[3];
  float* out = (float*)d_out;

  char* ws = (char*)d_ws;
  size_t off = 0;
  unsigned short* WT = (unsigned short*)(ws + off); off += (size_t)F_OUT * F_IN * 2;
  unsigned short* Xb = (unsigned short*)(ws + off); off += (size_t)N_NODES * F_IN * 2;
  unsigned short* hT = (unsigned short*)(ws + off); off += (size_t)F_OUT * N_NODES * 2;
  f32x4* rowdat = (f32x4*)(ws + off); off += (size_t)N_NODES * 16;
  unsigned* pE = (unsigned*)(ws + off); off += (size_t)N_NODES * 4;
  float* wa = (float*)(ws + off); off += (size_t)2 * F_IN * 4;
  unsigned long long* mask = (unsigned long long*)(ws + off);
  off += (size_t)N_NODES * (N_NODES / 64) * 8;   // 8 MB
  float* accws = (float*)(ws + off); off += (size_t)JS * N_NODES * F_OUT * 4;
  float* denws = (float*)(ws + off); off += (size_t)JS * N_NODES * 4;
  (void)in_sizes; (void)n_in; (void)out_size; (void)ws_size;

  k_mask<<<2048, 256, 0, stream>>>(adj, mask);
  k0a_wt<<<(F_IN * F_OUT) / 256, 256, 0, stream>>>(W, WT);
  k0c_wa<<<2, 256, 0, stream>>>(W, a, wa);
  k0b_x<<<N_NODES / 4, 256, 0, stream>>>(X, wa, Xb, rowdat, pE);
  k1_gemm<<<1024, 256, 0, stream>>>(WT, Xb, hT);
  k2_main<<<(N_NODES / 64) * JS, 256, 0, stream>>>((const unsigned*)mask, hT,
                                                   rowdat, pE, accws, denws);
  k3_fin<<<(N_NODES * F_OUT) / 4 / 256, 256, 0, stream>>>(accws, denws, out);
}

// Round 4
// 535.844 us; speedup vs baseline: 1.0303x; 1.0303x over previous
//
#include <hip/hip_runtime.h>
#include <hip/hip_bf16.h>

// GAT layer, N=8192, F_in=512, F_out=128.
// exp(leaky_relu(s1+s2)) = pos ? exp(s1)exp(s2) : exp(.2 s1)exp(.2 s2)
// r4: k2 re-tiled for hT-fragment reuse: each wave does 64 rows x 512 cols
// (4 row-tiles share every hT bf load -> L2 traffic /4), JS=16 -> 2048 waves
// (2/SIMD @ ~200 VGPR). Per 32-col step: build af[0..3], then 8x{bf load,
// 4 MFMA}. k_mask widened (4 ballots + 32B store per task).
// Known timed-window floor: ~160us ws-poison fill + ~80us d_in restore.

typedef __attribute__((ext_vector_type(4))) float f32x4;
typedef __attribute__((ext_vector_type(8))) short s16x8;

#define N_NODES 8192
#define F_IN 512
#define F_OUT 128
#define JS 16
#define WCOLS (N_NODES / JS)   // 512 cols per wave

static __device__ __forceinline__ short f2bf(float f) {
  __hip_bfloat16 h = __float2bfloat16(f);
  return __builtin_bit_cast(short, h);
}

// ------- k_mask: adj(int32 NxN) -> bitmask; 256 cols (4 words) per task ----
__global__ __launch_bounds__(256) void k_mask(const int* __restrict__ adj,
    unsigned long long* __restrict__ mask) {
  const int nwaves = gridDim.x * 4;
  int wid = blockIdx.x * 4 + (threadIdx.x >> 6);
  int lane = threadIdx.x & 63;
  const int ntasks = N_NODES * (N_NODES / 256);   // 262,144 wave-tasks
  for (int task = wid; task < ntasks; task += nwaves) {
    int row = task >> 5;
    int cg = task & 31;
    const int* p = adj + (size_t)row * N_NODES + cg * 256 + lane;
    int v0 = p[0], v1 = p[64], v2 = p[128], v3 = p[192];
    unsigned long long b0 = __ballot(v0 != 0);
    unsigned long long b1 = __ballot(v1 != 0);
    unsigned long long b2 = __ballot(v2 != 0);
    unsigned long long b3 = __ballot(v3 != 0);
    if (lane == 0) {
      unsigned long long* q = mask + (size_t)row * (N_NODES / 64) + cg * 4;
      ulonglong2 w0; w0.x = b0; w0.y = b1;
      ulonglong2 w1; w1.x = b2; w1.y = b3;
      *(ulonglong2*)(q) = w0;
      *(ulonglong2*)(q + 2) = w1;
    }
  }
}

// ---------------- k0a: W (512x128 f32) -> WT (128x512 bf16) ----------------
__global__ void k0a_wt(const float* __restrict__ W, unsigned short* __restrict__ WT) {
  int idx = blockIdx.x * 256 + threadIdx.x;
  int k = idx >> 7, f = idx & 127;
  WT[(size_t)f * F_IN + k] = (unsigned short)f2bf(W[idx]);
}

// ---------------- k0c: wa1[k] = sum_f W[k][f] a1[f]; wa2 likewise ----------
__global__ void k0c_wa(const float* __restrict__ W, const float* __restrict__ a,
                       float* __restrict__ wa) {
  int k = blockIdx.x * 256 + threadIdx.x;
  if (k >= F_IN) return;
  const float* Wr = W + (size_t)k * F_OUT;
  float d1 = 0.f, d2 = 0.f;
#pragma unroll 8
  for (int f = 0; f < F_OUT; f += 4) {
    f32x4 w  = *(const f32x4*)(Wr + f);
    f32x4 a1 = *(const f32x4*)(a + f);
    f32x4 a2 = *(const f32x4*)(a + F_OUT + f);
    d1 += w[0] * a1[0] + w[1] * a1[1] + w[2] * a1[2] + w[3] * a1[3];
    d2 += w[0] * a2[0] + w[1] * a2[1] + w[2] * a2[2] + w[3] * a2[3];
  }
  wa[k] = d1;
  wa[F_IN + k] = d2;
}

// ------- k0b: Xb = bf16(X); s1,s2 = X@wa per row; rowdat + pE tables -------
__global__ __launch_bounds__(256) void k0b_x(const float* __restrict__ X,
    const float* __restrict__ wa, unsigned short* __restrict__ Xb,
    f32x4* __restrict__ rowdat, unsigned* __restrict__ pE) {
  int wave = threadIdx.x >> 6, lane = threadIdx.x & 63;
  int i = blockIdx.x * 4 + wave;            // one wave per row
  const float* Xr = X + (size_t)i * F_IN + lane * 8;
  f32x4 x0 = ((const f32x4*)Xr)[0];
  f32x4 x1 = ((const f32x4*)Xr)[1];
  f32x4 w10 = ((const f32x4*)(wa + lane * 8))[0];
  f32x4 w11 = ((const f32x4*)(wa + lane * 8))[1];
  f32x4 w20 = ((const f32x4*)(wa + F_IN + lane * 8))[0];
  f32x4 w21 = ((const f32x4*)(wa + F_IN + lane * 8))[1];

  s16x8 xb;
#pragma unroll
  for (int e = 0; e < 4; e++) { xb[e] = f2bf(x0[e]); xb[e + 4] = f2bf(x1[e]); }
  *(s16x8*)(Xb + (size_t)i * F_IN + lane * 8) = xb;

  float d1 = 0.f, d2 = 0.f;
#pragma unroll
  for (int e = 0; e < 4; e++) {
    d1 += x0[e] * w10[e] + x1[e] * w11[e];
    d2 += x0[e] * w20[e] + x1[e] * w21[e];
  }
#pragma unroll
  for (int m = 1; m < 64; m <<= 1) {
    d1 += __shfl_xor(d1, m, 64);
    d2 += __shfl_xor(d2, m, 64);
  }
  if (lane == 0) {
    float s1 = d1, s2 = d2;
    f32x4 rd;
    rd[0] = expf(s1);          // E1
    rd[1] = expf(0.2f * s1);   // E1s
    rd[2] = expf(-s1);         // T1: pos <=> E2 > T1
    rd[3] = 0.f;
    rowdat[i] = rd;
    unsigned e2  = (unsigned)(unsigned short)f2bf(expf(s2));
    unsigned e2s = (unsigned)(unsigned short)f2bf(expf(0.2f * s2));
    pE[i] = (e2s << 16) | e2;
  }
}

// ------- k1: hT[f][node] = sum_k WT[f][k] Xb[node][k]; 1 tile per wave -----
__global__ __launch_bounds__(256) void k1_gemm(const unsigned short* __restrict__ WT,
    const unsigned short* __restrict__ Xb, unsigned short* __restrict__ hT) {
  int wave = threadIdx.x >> 6, lane = threadIdx.x & 63;
  int lrow = lane & 15, grp = lane >> 4;
  int tile = blockIdx.x * 4 + wave;              // 4096 tiles
  int fb = tile & 7;                             // 8 f-tiles of 16
  int nb = tile >> 3;                            // 512 node-tiles of 16

  const unsigned short* Ar = WT + (size_t)(fb * 16 + lrow) * F_IN + grp * 8;
  const unsigned short* Br = Xb + (size_t)(nb * 16 + lrow) * F_IN + grp * 8;

  f32x4 acc = (f32x4)(0.0f);
#pragma unroll
  for (int k0 = 0; k0 < F_IN; k0 += 32) {
    s16x8 af = *(const s16x8*)(Ar + k0);
    s16x8 bf = *(const s16x8*)(Br + k0);
    acc = __builtin_amdgcn_mfma_f32_16x16x32_bf16(af, bf, acc, 0, 0, 0);
  }
#pragma unroll
  for (int r = 0; r < 4; r++)
    hT[(size_t)(fb * 16 + grp * 4 + r) * N_NODES + nb * 16 + lrow] =
        (unsigned short)f2bf(acc[r]);
}

// ------- k2: 64 rows x 512 cols per wave; hT fragments reused 4x -----------
__global__ __launch_bounds__(256, 2) void k2_main(const unsigned* __restrict__ mask32,
    const unsigned short* __restrict__ hT, const f32x4* __restrict__ rowdat,
    const unsigned* __restrict__ pE, float* __restrict__ accws,
    float* __restrict__ denws) {
  int wave = threadIdx.x >> 6, lane = threadIdx.x & 63;
  int lrow = lane & 15, grp = lane >> 4;
  int rb = blockIdx.x >> 2;                 // 0..127
  int js = (blockIdx.x & 3) * 4 + wave;     // 0..15
  int rbase = rb * 64;
  int jlo = js * WCOLS;

  float E1[4], E1s[4], T1[4];
#pragma unroll
  for (int rt = 0; rt < 4; rt++) {
    f32x4 rd = rowdat[rbase + rt * 16 + lrow];
    E1[rt] = rd[0]; E1s[rt] = rd[1]; T1[rt] = rd[2];
  }

  f32x4 acc[4][8];
#pragma unroll
  for (int rt = 0; rt < 4; rt++)
#pragma unroll
    for (int n = 0; n < 8; n++) acc[rt][n] = (f32x4)(0.0f);
  float dsum[4] = {0.f, 0.f, 0.f, 0.f};

#define PROC1(rt, pe, e)                                              \
  {                                                                   \
    unsigned pu = (pe);                                               \
    float E2  = __builtin_bit_cast(float, pu << 16);                  \
    float E2s = __builtin_bit_cast(float, pu & 0xffff0000u);          \
    float sel = (E2 > T1[rt]) ? E1[rt] * E2 : E1s[rt] * E2s;          \
    float p = ((b >> (e)) & 1u) ? sel : 0.f;                          \
    dsum[rt] += p;                                                    \
    af[rt][e] = f2bf(p);                                              \
  }

  for (int sc = 0; sc < 4; sc++) {
    int jb = jlo + sc * 128;
    uint4 mm[4];
#pragma unroll
    for (int rt = 0; rt < 4; rt++)
      mm[rt] = *(const uint4*)(mask32 +
          (size_t)(rbase + rt * 16 + lrow) * (N_NODES / 32) + jb / 32);

#pragma unroll
    for (int t = 0; t < 4; t++) {
      int jj = jb + t * 32 + grp * 8;
      const uint4* pp = (const uint4*)(pE + jj);
      uint4 P0 = pp[0], P1 = pp[1];
      s16x8 af[4];
#pragma unroll
      for (int rt = 0; rt < 4; rt++) {
        unsigned b = (mm[rt][t] >> (grp * 8)) & 0xffu;
        PROC1(rt, P0.x, 0); PROC1(rt, P0.y, 1);
        PROC1(rt, P0.z, 2); PROC1(rt, P0.w, 3);
        PROC1(rt, P1.x, 4); PROC1(rt, P1.y, 5);
        PROC1(rt, P1.z, 6); PROC1(rt, P1.w, 7);
      }
#pragma unroll
      for (int n = 0; n < 8; n++) {
        s16x8 bf = *(const s16x8*)(hT + (size_t)(n * 16 + lrow) * N_NODES + jj);
#pragma unroll
        for (int rt = 0; rt < 4; rt++)
          acc[rt][n] =
              __builtin_amdgcn_mfma_f32_16x16x32_bf16(af[rt], bf, acc[rt][n], 0, 0, 0);
      }
    }
  }
#undef PROC1

  // row denominators: lanes {l, l^16, l^32, l^48} share the same row
#pragma unroll
  for (int rt = 0; rt < 4; rt++) {
    float d = dsum[rt];
    d += __shfl_xor(d, 16, 64);
    d += __shfl_xor(d, 32, 64);
    if (lane < 16) denws[js * N_NODES + rbase + rt * 16 + lane] = d;
  }

#pragma unroll
  for (int rt = 0; rt < 4; rt++)
#pragma unroll
    for (int n = 0; n < 8; n++)
#pragma unroll
      for (int r = 0; r < 4; r++)
        accws[((size_t)js * N_NODES + rbase + rt * 16 + grp * 4 + r) * F_OUT +
              n * 16 + lrow] = acc[rt][n][r];
}

// ---------------- k3: combine partials, normalize, elu (float4) -----------
__global__ void k3_fin(const float* __restrict__ accws,
                       const float* __restrict__ denws, float* __restrict__ out) {
  int idx4 = blockIdx.x * 256 + threadIdx.x;    // 262144 float4s
  int i = idx4 >> 5;
  const int S4 = N_NODES * F_OUT / 4;
  f32x4 s = (f32x4)(0.0f);
  float d = 0.f;
#pragma unroll
  for (int js = 0; js < JS; js++) {
    s += ((const f32x4*)accws)[idx4 + (size_t)js * S4];
    d += denws[i + js * N_NODES];
  }
  f32x4 v = s / d;
#pragma unroll
  for (int e = 0; e < 4; e++) v[e] = v[e] > 0.f ? v[e] : expm1f(v[e]);
  ((f32x4*)out)[idx4] = v;
}

extern "C" void kernel_launch(void* const* d_in, const int* in_sizes, int n_in,
                              void* d_out, int out_size, void* d_ws, size_t ws_size,
                              hipStream_t stream) {
  const float* X   = (const float*)d_in[0];
  const int*   adj = (const int*)d_in[1];
  const float* W   = (const float*)d_in[2];
  const float* a   = (const float*)d_in[3];
  float* out = (float*)d_out;

  char* ws = (char*)d_ws;
  size_t off = 0;
  unsigned short* WT = (unsigned short*)(ws + off); off += (size_t)F_OUT * F_IN * 2;
  unsigned short* Xb = (unsigned short*)(ws + off); off += (size_t)N_NODES * F_IN * 2;
  unsigned short* hT = (unsigned short*)(ws + off); off += (size_t)F_OUT * N_NODES * 2;
  f32x4* rowdat = (f32x4*)(ws + off); off += (size_t)N_NODES * 16;
  unsigned* pE = (unsigned*)(ws + off); off += (size_t)N_NODES * 4;
  float* wa = (float*)(ws + off); off += (size_t)2 * F_IN * 4;
  unsigned long long* mask = (unsigned long long*)(ws + off);
  off += (size_t)N_NODES * (N_NODES / 64) * 8;   // 8 MB
  float* accws = (float*)(ws + off); off += (size_t)JS * N_NODES * F_OUT * 4;
  float* denws = (float*)(ws + off); off += (size_t)JS * N_NODES * 4;
  (void)in_sizes; (void)n_in; (void)out_size; (void)ws_size;

  k_mask<<<2048, 256, 0, stream>>>(adj, mask);
  k0a_wt<<<(F_IN * F_OUT) / 256, 256, 0, stream>>>(W, WT);
  k0c_wa<<<2, 256, 0, stream>>>(W, a, wa);
  k0b_x<<<N_NODES / 4, 256, 0, stream>>>(X, wa, Xb, rowdat, pE);
  k1_gemm<<<1024, 256, 0, stream>>>(WT, Xb, hT);
  k2_main<<<(N_NODES / 64) * (JS / 4), 256, 0, stream>>>((const unsigned*)mask, hT,
                                                         rowdat, pE, accws, denws);
  k3_fin<<<(N_NODES * F_OUT) / 4 / 256, 256, 0, stream>>>(accws, denws, out);
}

// Round 5
// 518.703 us; speedup vs baseline: 1.0644x; 1.0330x over previous
//
#include <hip/hip_runtime.h>
#include <hip/hip_bf16.h>

// GAT layer, N=8192, F_in=512, F_out=128.
// exp(leaky_relu(s1+s2)) = pos ? exp(s1)exp(s2) : exp(.2 s1)exp(.2 s2)
// r5: 4 dispatches (block-role merge). kB overlaps adj->mask stream (BW) with
// h GEMM (MFMA) and row-table pass. kC reduces the 4 waves' partials in LDS
// (same 64 rows per block) -> accws 4 slices (16MB) instead of 16 (64MB).
// Harness floor (uncontrollable): ~160us 1GiB ws poison + ~80us input restore.

typedef __attribute__((ext_vector_type(4))) float f32x4;
typedef __attribute__((ext_vector_type(8))) short s16x8;

#define N_NODES 8192
#define F_IN 512
#define F_OUT 128
#define JS 16
#define WCOLS (N_NODES / JS)   // 512 cols per wave in kC

static __device__ __forceinline__ short f2bf(float f) {
  __hip_bfloat16 h = __float2bfloat16(f);
  return __builtin_bit_cast(short, h);
}

// ---------------- kA: {W->WT bf16} ∪ {wa = W@a1, W@a2} ----------------
__global__ __launch_bounds__(256) void kA(const float* __restrict__ W,
    const float* __restrict__ a, unsigned short* __restrict__ WT,
    float* __restrict__ wa) {
  int b = blockIdx.x;
  if (b < 256) {
    int idx = b * 256 + threadIdx.x;
    int k = idx >> 7, f = idx & 127;
    WT[(size_t)f * F_IN + k] = (unsigned short)f2bf(W[idx]);
  } else {
    int k = (b - 256) * 256 + threadIdx.x;
    if (k < F_IN) {
      const float* Wr = W + (size_t)k * F_OUT;
      float d1 = 0.f, d2 = 0.f;
#pragma unroll 8
      for (int f = 0; f < F_OUT; f += 4) {
        f32x4 w  = *(const f32x4*)(Wr + f);
        f32x4 a1 = *(const f32x4*)(a + f);
        f32x4 a2 = *(const f32x4*)(a + F_OUT + f);
        d1 += w[0] * a1[0] + w[1] * a1[1] + w[2] * a1[2] + w[3] * a1[3];
        d2 += w[0] * a2[0] + w[1] * a2[1] + w[2] * a2[2] + w[3] * a2[3];
      }
      wa[k] = d1;
      wa[F_IN + k] = d2;
    }
  }
}

// ------- kB: {adj->mask} ∪ {rowdat/pE from X@wa} ∪ {hT GEMM, inline cvt} ----
__global__ __launch_bounds__(256) void kB(const int* __restrict__ adj,
    unsigned long long* __restrict__ mask, const float* __restrict__ X,
    const float* __restrict__ wa, const unsigned short* __restrict__ WT,
    f32x4* __restrict__ rowdat, unsigned* __restrict__ pE,
    unsigned short* __restrict__ hT) {
  int b = blockIdx.x;
  int wave = threadIdx.x >> 6, lane = threadIdx.x & 63;

  if (b < 4096) {
    // ---- adj -> bitmask; 256 cols per task, 4 ballots + 32B store ----
    const int nwaves = 4096 * 4;
    int wid = b * 4 + wave;
    const int ntasks = N_NODES * (N_NODES / 256);   // 262,144
    for (int task = wid; task < ntasks; task += nwaves) {
      int row = task >> 5;
      int cg = task & 31;
      const int* p = adj + (size_t)row * N_NODES + cg * 256 + lane;
      int v0 = p[0], v1 = p[64], v2 = p[128], v3 = p[192];
      unsigned long long b0 = __ballot(v0 != 0);
      unsigned long long b1 = __ballot(v1 != 0);
      unsigned long long b2 = __ballot(v2 != 0);
      unsigned long long b3 = __ballot(v3 != 0);
      if (lane == 0) {
        unsigned long long* q = mask + (size_t)row * (N_NODES / 64) + cg * 4;
        ulonglong2 w0; w0.x = b0; w0.y = b1;
        ulonglong2 w1; w1.x = b2; w1.y = b3;
        *(ulonglong2*)(q) = w0;
        *(ulonglong2*)(q + 2) = w1;
      }
    }
  } else if (b < 6144) {
    // ---- per-row s1,s2 = X@wa -> rowdat, pE ----
    int i = (b - 4096) * 4 + wave;
    const float* Xr = X + (size_t)i * F_IN + lane * 8;
    f32x4 x0 = ((const f32x4*)Xr)[0];
    f32x4 x1 = ((const f32x4*)Xr)[1];
    f32x4 w10 = ((const f32x4*)(wa + lane * 8))[0];
    f32x4 w11 = ((const f32x4*)(wa + lane * 8))[1];
    f32x4 w20 = ((const f32x4*)(wa + F_IN + lane * 8))[0];
    f32x4 w21 = ((const f32x4*)(wa + F_IN + lane * 8))[1];
    float d1 = 0.f, d2 = 0.f;
#pragma unroll
    for (int e = 0; e < 4; e++) {
      d1 += x0[e] * w10[e] + x1[e] * w11[e];
      d2 += x0[e] * w20[e] + x1[e] * w21[e];
    }
#pragma unroll
    for (int m = 1; m < 64; m <<= 1) {
      d1 += __shfl_xor(d1, m, 64);
      d2 += __shfl_xor(d2, m, 64);
    }
    if (lane == 0) {
      float s1 = d1, s2 = d2;
      f32x4 rd;
      rd[0] = expf(s1);          // E1
      rd[1] = expf(0.2f * s1);   // E1s
      rd[2] = expf(-s1);         // T1: pos <=> E2 > T1
      rd[3] = 0.f;
      rowdat[i] = rd;
      unsigned e2  = (unsigned)(unsigned short)f2bf(expf(s2));
      unsigned e2s = (unsigned)(unsigned short)f2bf(expf(0.2f * s2));
      pE[i] = (e2s << 16) | e2;
    }
  } else {
    // ---- hT[f][node] GEMM; B operand = X converted inline ----
    int lrow = lane & 15, grp = lane >> 4;
    int tile = (b - 6144) * 4 + wave;              // 4096 tiles
    int fb = tile & 7;
    int nb = tile >> 3;
    const unsigned short* Ar = WT + (size_t)(fb * 16 + lrow) * F_IN + grp * 8;
    const float* Br = X + (size_t)(nb * 16 + lrow) * F_IN + grp * 8;

    f32x4 acc = (f32x4)(0.0f);
#pragma unroll
    for (int k0 = 0; k0 < F_IN; k0 += 32) {
      s16x8 af = *(const s16x8*)(Ar + k0);
      f32x4 b0 = *(const f32x4*)(Br + k0);
      f32x4 b1 = *(const f32x4*)(Br + k0 + 4);
      s16x8 bf;
#pragma unroll
      for (int e = 0; e < 4; e++) { bf[e] = f2bf(b0[e]); bf[e + 4] = f2bf(b1[e]); }
      acc = __builtin_amdgcn_mfma_f32_16x16x32_bf16(af, bf, acc, 0, 0, 0);
    }
#pragma unroll
    for (int r = 0; r < 4; r++)
      hT[(size_t)(fb * 16 + grp * 4 + r) * N_NODES + nb * 16 + lrow] =
          (unsigned short)f2bf(acc[r]);
  }
}

// ------- kC: 64 rows x 512 cols per wave; LDS cross-wave (js) reduction ----
__global__ __launch_bounds__(256, 2) void kC(const unsigned* __restrict__ mask32,
    const unsigned short* __restrict__ hT, const f32x4* __restrict__ rowdat,
    const unsigned* __restrict__ pE, float* __restrict__ accws,
    float* __restrict__ denws) {
  __shared__ float red[4][16 * 132];
  __shared__ float sden[4][4][16];

  int wave = threadIdx.x >> 6, lane = threadIdx.x & 63;
  int lrow = lane & 15, grp = lane >> 4;
  int rb = blockIdx.x >> 2;                 // 0..127
  int q = blockIdx.x & 3;                   // slice
  int js = q * 4 + wave;                    // 0..15
  int rbase = rb * 64;
  int jlo = js * WCOLS;

  float E1[4], E1s[4], T1[4];
#pragma unroll
  for (int rt = 0; rt < 4; rt++) {
    f32x4 rd = rowdat[rbase + rt * 16 + lrow];
    E1[rt] = rd[0]; E1s[rt] = rd[1]; T1[rt] = rd[2];
  }

  f32x4 acc[4][8];
#pragma unroll
  for (int rt = 0; rt < 4; rt++)
#pragma unroll
    for (int n = 0; n < 8; n++) acc[rt][n] = (f32x4)(0.0f);
  float dsum[4] = {0.f, 0.f, 0.f, 0.f};

#define PROC1(rt, pe, e)                                              \
  {                                                                   \
    unsigned pu = (pe);                                               \
    float E2  = __builtin_bit_cast(float, pu << 16);                  \
    float E2s = __builtin_bit_cast(float, pu & 0xffff0000u);          \
    float sel = (E2 > T1[rt]) ? E1[rt] * E2 : E1s[rt] * E2s;          \
    float p = ((bm >> (e)) & 1u) ? sel : 0.f;                         \
    dsum[rt] += p;                                                    \
    af[rt][e] = f2bf(p);                                              \
  }

  for (int sc = 0; sc < 4; sc++) {
    int jb = jlo + sc * 128;
    uint4 mm[4];
#pragma unroll
    for (int rt = 0; rt < 4; rt++)
      mm[rt] = *(const uint4*)(mask32 +
          (size_t)(rbase + rt * 16 + lrow) * (N_NODES / 32) + jb / 32);

#pragma unroll
    for (int t = 0; t < 4; t++) {
      int jj = jb + t * 32 + grp * 8;
      const uint4* pp = (const uint4*)(pE + jj);
      uint4 P0 = pp[0], P1 = pp[1];
      s16x8 af[4];
#pragma unroll
      for (int rt = 0; rt < 4; rt++) {
        unsigned bm = (mm[rt][t] >> (grp * 8)) & 0xffu;
        PROC1(rt, P0.x, 0); PROC1(rt, P0.y, 1);
        PROC1(rt, P0.z, 2); PROC1(rt, P0.w, 3);
        PROC1(rt, P1.x, 4); PROC1(rt, P1.y, 5);
        PROC1(rt, P1.z, 6); PROC1(rt, P1.w, 7);
      }
#pragma unroll
      for (int n = 0; n < 8; n++) {
        s16x8 bf = *(const s16x8*)(hT + (size_t)(n * 16 + lrow) * N_NODES + jj);
#pragma unroll
        for (int rt = 0; rt < 4; rt++)
          acc[rt][n] =
              __builtin_amdgcn_mfma_f32_16x16x32_bf16(af[rt], bf, acc[rt][n], 0, 0, 0);
      }
    }
  }
#undef PROC1

  // den partials (lanes l, l^16, l^32, l^48 share the same row)
#pragma unroll
  for (int rt = 0; rt < 4; rt++) {
    float d = dsum[rt];
    d += __shfl_xor(d, 16, 64);
    d += __shfl_xor(d, 32, 64);
    if (lane < 16) sden[wave][rt][lane] = d;
  }

  // LDS reduce the 4 waves' acc (same rows, different js) -> slice q
#pragma unroll
  for (int rt = 0; rt < 4; rt++) {
    __syncthreads();
#pragma unroll
    for (int n = 0; n < 8; n++)
#pragma unroll
      for (int r = 0; r < 4; r++)
        red[wave][(grp * 4 + r) * 132 + n * 16 + lrow] = acc[rt][n][r];
    __syncthreads();
    int e0 = threadIdx.x * 8;
    int row16 = e0 >> 7, col = e0 & 127;
    int li = row16 * 132 + col;
    f32x4 s0 = *(f32x4*)&red[0][li] + *(f32x4*)&red[1][li] +
               *(f32x4*)&red[2][li] + *(f32x4*)&red[3][li];
    f32x4 s1 = *(f32x4*)&red[0][li + 4] + *(f32x4*)&red[1][li + 4] +
               *(f32x4*)&red[2][li + 4] + *(f32x4*)&red[3][li + 4];
    float* dst = accws +
        ((size_t)q * N_NODES + rbase + rt * 16 + row16) * F_OUT + col;
    *(f32x4*)dst = s0;
    *(f32x4*)(dst + 4) = s1;
  }
  __syncthreads();
  if (threadIdx.x < 64) {
    int rt = threadIdx.x >> 4, r16 = threadIdx.x & 15;
    float d = sden[0][rt][r16] + sden[1][rt][r16] +
              sden[2][rt][r16] + sden[3][rt][r16];
    denws[q * N_NODES + rbase + threadIdx.x] = d;
  }
}

// ---------------- kD: combine 4 slices, normalize, elu (float4) -----------
__global__ void kD(const float* __restrict__ accws,
                   const float* __restrict__ denws, float* __restrict__ out) {
  int idx4 = blockIdx.x * 256 + threadIdx.x;    // 262144 float4s
  int i = idx4 >> 5;
  const int S4 = N_NODES * F_OUT / 4;
  f32x4 s = (f32x4)(0.0f);
  float d = 0.f;
#pragma unroll
  for (int q = 0; q < 4; q++) {
    s += ((const f32x4*)accws)[idx4 + (size_t)q * S4];
    d += denws[i + q * N_NODES];
  }
  f32x4 v = s / d;
#pragma unroll
  for (int e = 0; e < 4; e++) v[e] = v[e] > 0.f ? v[e] : expm1f(v[e]);
  ((f32x4*)out)[idx4] = v;
}

extern "C" void kernel_launch(void* const* d_in, const int* in_sizes, int n_in,
                              void* d_out, int out_size, void* d_ws, size_t ws_size,
                              hipStream_t stream) {
  const float* X   = (const float*)d_in[0];
  const int*   adj = (const int*)d_in[1];
  const float* W   = (const float*)d_in[2];
  const float* a   = (const float*)d_in[3];
  float* out = (float*)d_out;

  char* ws = (char*)d_ws;
  size_t off = 0;
  unsigned short* WT = (unsigned short*)(ws + off); off += (size_t)F_OUT * F_IN * 2;
  unsigned short* hT = (unsigned short*)(ws + off); off += (size_t)F_OUT * N_NODES * 2;
  f32x4* rowdat = (f32x4*)(ws + off); off += (size_t)N_NODES * 16;
  unsigned* pE = (unsigned*)(ws + off); off += (size_t)N_NODES * 4;
  float* wa = (float*)(ws + off); off += (size_t)2 * F_IN * 4;
  unsigned long long* mask = (unsigned long long*)(ws + off);
  off += (size_t)N_NODES * (N_NODES / 64) * 8;   // 8 MB
  float* accws = (float*)(ws + off); off += (size_t)4 * N_NODES * F_OUT * 4; // 16MB
  float* denws = (float*)(ws + off); off += (size_t)4 * N_NODES * 4;
  (void)in_sizes; (void)n_in; (void)out_size; (void)ws_size;

  kA<<<258, 256, 0, stream>>>(W, a, WT, wa);
  kB<<<7168, 256, 0, stream>>>(adj, mask, X, wa, WT, rowdat, pE, hT);
  kC<<<(N_NODES / 64) * 4, 256, 0, stream>>>((const unsigned*)mask, hT,
                                             rowdat, pE, accws, denws);
  kD<<<(N_NODES * F_OUT) / 4 / 256, 256, 0, stream>>>(accws, denws, out);
}

// Round 6
// 518.520 us; speedup vs baseline: 1.0648x; 1.0004x over previous
//
#include <hip/hip_runtime.h>
#include <hip/hip_bf16.h>

// GAT layer, N=8192, F_in=512, F_out=128.
// exp(leaky_relu(s1+s2)) = pos ? exp(s1)exp(s2) : exp(.2 s1)exp(.2 s2)
// r6: no mask pass. kMain streams adj directly with row-contiguous loads
// (lane = 16B of ONE row; the previous rounds' lrow-dependent loads made 64
// lanes hit 64 scattered cache lines -> 540 GB/s). P routed through an LDS
// tile to form MFMA A-fragments; reg-prefetch of next chunk; each block owns
// 16 rows x all cols so it finalizes its own rows (no partial buffers).
// Floor (uncontrollable): ~160us 1GiB ws poison + ~85us input restore.

typedef __attribute__((ext_vector_type(4))) float f32x4;
typedef __attribute__((ext_vector_type(8))) short s16x8;

#define N_NODES 8192
#define F_IN 512
#define F_OUT 128
#define CHUNK 256
#define NCHUNK (N_NODES / CHUNK)   // 32
#define PSTRIDE 272                // bf16 elems; 544 B rows -> <=4-way LDS conflicts

static __device__ __forceinline__ short f2bf(float f) {
  __hip_bfloat16 h = __float2bfloat16(f);
  return __builtin_bit_cast(short, h);
}

// ---------------- kA: {W->WT bf16} ∪ {wa = W@a1, W@a2} ----------------
__global__ __launch_bounds__(256) void kA(const float* __restrict__ W,
    const float* __restrict__ a, unsigned short* __restrict__ WT,
    float* __restrict__ wa) {
  int b = blockIdx.x;
  if (b < 256) {
    int idx = b * 256 + threadIdx.x;
    int k = idx >> 7, f = idx & 127;
    WT[(size_t)f * F_IN + k] = (unsigned short)f2bf(W[idx]);
  } else {
    int k = (b - 256) * 256 + threadIdx.x;
    if (k < F_IN) {
      const float* Wr = W + (size_t)k * F_OUT;
      float d1 = 0.f, d2 = 0.f;
#pragma unroll 8
      for (int f = 0; f < F_OUT; f += 4) {
        f32x4 w  = *(const f32x4*)(Wr + f);
        f32x4 a1 = *(const f32x4*)(a + f);
        f32x4 a2 = *(const f32x4*)(a + F_OUT + f);
        d1 += w[0] * a1[0] + w[1] * a1[1] + w[2] * a1[2] + w[3] * a1[3];
        d2 += w[0] * a2[0] + w[1] * a2[1] + w[2] * a2[2] + w[3] * a2[3];
      }
      wa[k] = d1;
      wa[F_IN + k] = d2;
    }
  }
}

// ------- kStage: {hT GEMM (inline f32->bf16 B)} ∪ {rowdat/pE tables} -------
__global__ __launch_bounds__(256) void kStage(const float* __restrict__ X,
    const float* __restrict__ wa, const unsigned short* __restrict__ WT,
    f32x4* __restrict__ rowdat, unsigned* __restrict__ pE,
    unsigned short* __restrict__ hT) {
  int b = blockIdx.x;
  int wave = threadIdx.x >> 6, lane = threadIdx.x & 63;

  if (b < 1024) {
    // ---- hT[f][node] = sum_k WT[f][k] X[node][k] ----
    int lrow = lane & 15, grp = lane >> 4;
    int tile = b * 4 + wave;                       // 4096 tiles
    int fb = tile & 7;
    int nb = tile >> 3;
    const unsigned short* Ar = WT + (size_t)(fb * 16 + lrow) * F_IN + grp * 8;
    const float* Br = X + (size_t)(nb * 16 + lrow) * F_IN + grp * 8;

    f32x4 acc = (f32x4)(0.0f);
#pragma unroll
    for (int k0 = 0; k0 < F_IN; k0 += 32) {
      s16x8 af = *(const s16x8*)(Ar + k0);
      f32x4 b0 = *(const f32x4*)(Br + k0);
      f32x4 b1 = *(const f32x4*)(Br + k0 + 4);
      s16x8 bf;
#pragma unroll
      for (int e = 0; e < 4; e++) { bf[e] = f2bf(b0[e]); bf[e + 4] = f2bf(b1[e]); }
      acc = __builtin_amdgcn_mfma_f32_16x16x32_bf16(af, bf, acc, 0, 0, 0);
    }
#pragma unroll
    for (int r = 0; r < 4; r++)
      hT[(size_t)(fb * 16 + grp * 4 + r) * N_NODES + nb * 16 + lrow] =
          (unsigned short)f2bf(acc[r]);
  } else {
    // ---- per-row s1,s2 = X@wa -> rowdat, pE ----
    int i = (b - 1024) * 4 + wave;
    const float* Xr = X + (size_t)i * F_IN + lane * 8;
    f32x4 x0 = ((const f32x4*)Xr)[0];
    f32x4 x1 = ((const f32x4*)Xr)[1];
    f32x4 w10 = ((const f32x4*)(wa + lane * 8))[0];
    f32x4 w11 = ((const f32x4*)(wa + lane * 8))[1];
    f32x4 w20 = ((const f32x4*)(wa + F_IN + lane * 8))[0];
    f32x4 w21 = ((const f32x4*)(wa + F_IN + lane * 8))[1];
    float d1 = 0.f, d2 = 0.f;
#pragma unroll
    for (int e = 0; e < 4; e++) {
      d1 += x0[e] * w10[e] + x1[e] * w11[e];
      d2 += x0[e] * w20[e] + x1[e] * w21[e];
    }
#pragma unroll
    for (int m = 1; m < 64; m <<= 1) {
      d1 += __shfl_xor(d1, m, 64);
      d2 += __shfl_xor(d2, m, 64);
    }
    if (lane == 0) {
      float s1 = d1, s2 = d2;
      f32x4 rd;
      rd[0] = expf(s1);          // E1
      rd[1] = expf(0.2f * s1);   // E1s
      rd[2] = expf(-s1);         // T1: pos <=> E2 > T1
      rd[3] = 0.f;
      rowdat[i] = rd;
      unsigned e2  = (unsigned)(unsigned short)f2bf(expf(s2));
      unsigned e2s = (unsigned)(unsigned short)f2bf(expf(0.2f * s2));
      pE[i] = (e2s << 16) | e2;
    }
  }
}

// ------- kMain: direct-adj one-pass P@h + finalize; 16 rows x all cols -----
// Wave w computes p for rows w*4..w*4+3 (row-contiguous adj loads, 1KB/inst),
// stages bf16 P in LDS, then all waves MFMA their 32-feat slice against hT.
__global__ __launch_bounds__(256, 2) void kMain(const int* __restrict__ adj,
    const unsigned short* __restrict__ hT, const f32x4* __restrict__ rowdat,
    const unsigned* __restrict__ pE, float* __restrict__ out) {
  __shared__ unsigned short P_lds[16 * PSTRIDE];
  __shared__ float sden[16];

  int wave = threadIdx.x >> 6, lane = threadIdx.x & 63;
  int lrow = lane & 15, grp = lane >> 4;
  int rbase = blockIdx.x * 16;

  float E1[4], E1s[4], T1[4];
#pragma unroll
  for (int rr = 0; rr < 4; rr++) {
    f32x4 rd = rowdat[rbase + wave * 4 + rr];
    E1[rr] = rd[0]; E1s[rr] = rd[1]; T1[rr] = rd[2];
  }

  const int* adjbase = adj + (size_t)(rbase + wave * 4) * N_NODES + lane * 4;
  const unsigned* pEl = pE + lane * 4;

  float dsum[4] = {0.f, 0.f, 0.f, 0.f};
  f32x4 acc[2];
  acc[0] = (f32x4)(0.0f);
  acc[1] = (f32x4)(0.0f);

#define PROC1(av, pv, rr, pout)                                   \
  {                                                               \
    unsigned pu = (pv);                                           \
    float E2  = __builtin_bit_cast(float, pu << 16);              \
    float E2s = __builtin_bit_cast(float, pu & 0xffff0000u);      \
    float sel = (E2 > T1[rr]) ? E1[rr] * E2 : E1s[rr] * E2s;      \
    pout = ((av) != 0) ? sel : 0.f;                               \
    dsum[rr] += pout;                                             \
  }

#define PROCPACK(A4, P4, rr, lo, hi)                              \
  {                                                               \
    float p0, p1, p2, p3;                                         \
    PROC1(A4.x, P4.x, rr, p0) PROC1(A4.y, P4.y, rr, p1)           \
    PROC1(A4.z, P4.z, rr, p2) PROC1(A4.w, P4.w, rr, p3)           \
    lo = ((unsigned)(unsigned short)f2bf(p1) << 16) |             \
         (unsigned)(unsigned short)f2bf(p0);                      \
    hi = ((unsigned)(unsigned short)f2bf(p3) << 16) |             \
         (unsigned)(unsigned short)f2bf(p2);                      \
  }

#define BODY(USEA, USEP, PREA, PREP, C)                                        \
  {                                                                            \
    int cn = ((C) < NCHUNK - 1) ? (C) + 1 : 0;                                 \
    _Pragma("unroll")                                                          \
    for (int rr = 0; rr < 4; rr++)                                             \
      PREA[rr] = *(const int4*)(adjbase + (size_t)rr * N_NODES + cn * CHUNK);  \
    PREP = *(const uint4*)(pEl + cn * CHUNK);                                  \
    _Pragma("unroll")                                                          \
    for (int rr = 0; rr < 4; rr++) {                                           \
      unsigned lo, hi;                                                         \
      PROCPACK(USEA[rr], USEP, rr, lo, hi)                                     \
      *(uint2*)((char*)P_lds + (wave * 4 + rr) * (PSTRIDE * 2) + lane * 8) =   \
          make_uint2(lo, hi);                                                  \
    }                                                                          \
    __syncthreads();                                                           \
    _Pragma("unroll")                                                          \
    for (int t = 0; t < 8; t++) {                                              \
      s16x8 af = *(const s16x8*)((const char*)P_lds + lrow * (PSTRIDE * 2) +   \
                                 t * 64 + grp * 16);                           \
      int jj = (C) * CHUNK + t * 32 + grp * 8;                                 \
      _Pragma("unroll")                                                        \
      for (int nt = 0; nt < 2; nt++) {                                         \
        s16x8 bfv = *(const s16x8*)(hT +                                       \
            (size_t)(wave * 32 + nt * 16 + lrow) * N_NODES + jj);              \
        acc[nt] = __builtin_amdgcn_mfma_f32_16x16x32_bf16(af, bfv, acc[nt],    \
                                                          0, 0, 0);            \
      }                                                                        \
    }                                                                          \
    __syncthreads();                                                           \
  }

  int4 bufA[4], bufB[4];
  uint4 bufPA, bufPB;
#pragma unroll
  for (int rr = 0; rr < 4; rr++)
    bufA[rr] = *(const int4*)(adjbase + (size_t)rr * N_NODES);
  bufPA = *(const uint4*)(pEl);

  for (int cc = 0; cc < NCHUNK; cc += 2) {
    BODY(bufA, bufPA, bufB, bufPB, cc)
    BODY(bufB, bufPB, bufA, bufPA, cc + 1)
  }
#undef BODY
#undef PROCPACK
#undef PROC1

  // row denominators: reduce dsum[rr] across the wave's 64 lanes
#pragma unroll
  for (int rr = 0; rr < 4; rr++) {
    float d = dsum[rr];
#pragma unroll
    for (int m = 1; m < 64; m <<= 1) d += __shfl_xor(d, m, 64);
    if (lane == 0) sden[wave * 4 + rr] = d;
  }
  __syncthreads();

  // finalize: out[row][feat] = elu(acc/den); wave owns feats wave*32..+31
#pragma unroll
  for (int nt = 0; nt < 2; nt++)
#pragma unroll
    for (int r = 0; r < 4; r++) {
      int row = grp * 4 + r;
      float v = acc[nt][r] / sden[row];
      v = v > 0.f ? v : expm1f(v);
      out[(size_t)(rbase + row) * F_OUT + wave * 32 + nt * 16 + lrow] = v;
    }
}

extern "C" void kernel_launch(void* const* d_in, const int* in_sizes, int n_in,
                              void* d_out, int out_size, void* d_ws, size_t ws_size,
                              hipStream_t stream) {
  const float* X   = (const float*)d_in[0];
  const int*   adj = (const int*)d_in[1];
  const float* W   = (const float*)d_in[2];
  const float* a   = (const float*)d_in[3];
  float* out = (float*)d_out;

  char* ws = (char*)d_ws;
  size_t off = 0;
  unsigned short* WT = (unsigned short*)(ws + off); off += (size_t)F_OUT * F_IN * 2;
  unsigned short* hT = (unsigned short*)(ws + off); off += (size_t)F_OUT * N_NODES * 2;
  f32x4* rowdat = (f32x4*)(ws + off); off += (size_t)N_NODES * 16;
  unsigned* pE = (unsigned*)(ws + off); off += (size_t)N_NODES * 4;
  float* wa = (float*)(ws + off); off += (size_t)2 * F_IN * 4;
  (void)in_sizes; (void)n_in; (void)out_size; (void)ws_size;

  kA<<<258, 256, 0, stream>>>(W, a, WT, wa);
  kStage<<<3072, 256, 0, stream>>>(X, wa, WT, rowdat, pE, hT);
  kMain<<<N_NODES / 16, 256, 0, stream>>>(adj, hT, rowdat, pE, out);
}